// Round 11
// baseline (121.745 us; speedup 1.0000x reference)
//
#include <hip/hip_runtime.h>
#include <hip/hip_bf16.h>
#include <math.h>

#define BB 65536
#define DD 256
#define KK 10
#define LOG_2PI 1.8378770664093453f

// ---------------------------------------------------------------------------
// Prep: grid = K blocks x 256 threads.
// Transposed-for-coalescing layout: float4 slot (k*2 + half)*64 + f, where
// f = dim-quad 0..63 and half 0 = iv4, half 1 = -2*mu*iv4. Main's lane L
// loads its i-th coefficient as t4[i*64 + L] -> 20 perfectly-coalesced
// 1KB loads, after which ALL coefficients are VGPR-resident per-lane
// (no s_load / readlane / LDS anywhere in the hot loop). Also writes C[k].
// ---------------------------------------------------------------------------
__global__ __launch_bounds__(DD) void gmvae_prep(
    const float* __restrict__ mu_table,
    const float* __restrict__ logvar_table,
    float* __restrict__ tab,   // 2*K*D floats (20 KB)
    float* __restrict__ C)     // K floats
{
    const int k = blockIdx.x;
    const int d = threadIdx.x;
    const float lv = logvar_table[k * DD + d];
    const float m  = mu_table[k * DD + d];
    const float iv = expf(-lv);          // exact 1.0 when lv==0
    const float a  = m * iv;

    const int f    = d >> 2;             // dim-quad 0..63
    const int comp = d & 3;
    tab[((k * 2) * 64 + f) * 4 + comp]     = iv;
    tab[((k * 2 + 1) * 64 + f) * 4 + comp] = -2.0f * a;

    float p = fmaf(m, a, lv);            // mu^2*iv + lv
    __shared__ float red[4];
    #pragma unroll
    for (int off = 32; off > 0; off >>= 1)
        p += __shfl_down(p, off, 64);
    if ((threadIdx.x & 63) == 0)
        red[threadIdx.x >> 6] = p;
    __syncthreads();
    if (threadIdx.x == 0) {
        const float s2 = (red[0] + red[1]) + (red[2] + red[3]);
        C[k] = -0.5f * (s2 + 256.0f * LOG_2PI) + logf(0.1f);
    }
}

// Single-instruction DPP add steps (VALU pipe only, no LDS).
// CTRL: 0x121..0x12F = row_ror:N (within 16-lane rows),
//       0x142 = row_bcast15 (dest rows 1,3), 0x143 = row_bcast31 (rows 2,3).
// RMASK gates dest lanes; masked lanes take old=0 -> add 0.
template <int CTRL, int RMASK>
__device__ __forceinline__ float dpp_add(float v) {
    const int r = __builtin_amdgcn_update_dpp(
        0, __float_as_int(v), CTRL, RMASK, 0xF, true);
    return v + __int_as_float(r);
}

// Wave-wide sum of v; result valid in lanes 48..63 (DPP row 3).
__device__ __forceinline__ float wave_sum_hi(float v) {
    v = dpp_add<0x128, 0xF>(v);   // row_ror:8
    v = dpp_add<0x124, 0xF>(v);   // row_ror:4
    v = dpp_add<0x122, 0xF>(v);   // row_ror:2
    v = dpp_add<0x121, 0xF>(v);   // row_ror:1  -> each 16-row holds S_r
    v = dpp_add<0x142, 0xA>(v);   // bcast15: row1+=S0, row3+=S2
    v = dpp_add<0x143, 0xC>(v);   // bcast31: rows2,3 += (S0+S1) -> row3 total
    return v;
}

// ---------------------------------------------------------------------------
// Main. Block = 256 threads = 4 waves; wave handles 16 rows. Lane = dim-quad
// (64 lanes x 4 dims = all 256 dims). Per row: ONE coalesced 1KB q load,
// 80 FMA, 60 single-inst DPP adds, 10 cndmask. Coefficients VGPR-resident
// (wc[20] float4, loaded once, coalesced). NO LDS / barriers / s_load /
// readlane in the hot loop. Row j's totals land in keeper lane 48+j.
// grid = B/64 = 1024 blocks -> 4096 waves, 4/SIMD.
// ---------------------------------------------------------------------------
__global__ __launch_bounds__(256) void gmvae_main(
    const float* __restrict__ q_z,
    const float* __restrict__ tab,
    const float* __restrict__ C,
    float* __restrict__ out)
{
    const int t    = threadIdx.x;
    const int lane = t & 63;
    const int w    = t >> 6;
    const int base = blockIdx.x * 64 + w * 16;   // wave's first row

    const float4* __restrict__ q4 = reinterpret_cast<const float4*>(q_z);
    const float4* __restrict__ t4 = reinterpret_cast<const float4*>(tab);

    // one-time coefficient load: wc[k*2]=iv4, wc[k*2+1]=na4 for lane's quad
    float4 wc[20];
    #pragma unroll
    for (int i = 0; i < 20; ++i)
        wc[i] = t4[i * 64 + lane];

    float keep[KK];
    #pragma unroll
    for (int k = 0; k < KK; ++k) keep[k] = 0.f;

    // rolling 4-deep q prefetch
    float4 qb[4];
    #pragma unroll
    for (int j = 0; j < 4; ++j)
        qb[j] = q4[(size_t)(base + j) * 64 + lane];

    #pragma unroll
    for (int j = 0; j < 16; ++j) {
        const float4 q = qb[j & 3];
        if (j < 12)
            qb[j & 3] = q4[(size_t)(base + j + 4) * 64 + lane];
        const float qx2 = q.x * q.x, qy2 = q.y * q.y;
        const float qz2 = q.z * q.z, qw2 = q.w * q.w;
        #pragma unroll
        for (int k = 0; k < KK; ++k) {
            const float4 iv = wc[2 * k];
            const float4 na = wc[2 * k + 1];
            float a = 0.f;
            a = fmaf(qx2, iv.x, a);
            a = fmaf(q.x, na.x, a);
            a = fmaf(qy2, iv.y, a);
            a = fmaf(q.y, na.y, a);
            a = fmaf(qz2, iv.z, a);
            a = fmaf(q.z, na.z, a);
            a = fmaf(qw2, iv.w, a);
            a = fmaf(q.w, na.w, a);
            a = wave_sum_hi(a);                      // total in lanes 48..63
            keep[k] = (lane == 48 + j) ? a : keep[k];
        }
    }

    // epilogue: keeper lanes 48..63 own rows base..base+15
    if (lane >= 48) {
        const int row = base + (lane - 48);
        float l[KK];
        #pragma unroll
        for (int k = 0; k < KK; ++k)
            l[k] = fmaf(keep[k], -0.5f, C[k]);

        float mx = l[0];
        #pragma unroll
        for (int k = 1; k < KK; ++k) mx = fmaxf(mx, l[k]);

        float e[KK];
        float sum = 0.f;
        #pragma unroll
        for (int k = 0; k < KK; ++k) { e[k] = __expf(l[k] - mx); sum += e[k]; }
        const float inv = 1.0f / sum;

        int idx = 0;
        float best = l[0];
        #pragma unroll
        for (int k = 1; k < KK; ++k)
            if (l[k] > best) { best = l[k]; idx = k; }

        float2* __restrict__ o1 =
            reinterpret_cast<float2*>(out) + (size_t)row * 5;
        float2* __restrict__ o2 =
            reinterpret_cast<float2*>(out + (size_t)BB * KK) + (size_t)row * 5;
        #pragma unroll
        for (int k = 0; k < 5; ++k)
            o1[k] = make_float2(l[2 * k], l[2 * k + 1]);
        #pragma unroll
        for (int k = 0; k < 5; ++k)
            o2[k] = make_float2(e[2 * k] * inv, e[2 * k + 1] * inv);
        out[(size_t)2 * BB * KK + row] = (float)idx;
    }
}

extern "C" void kernel_launch(void* const* d_in, const int* in_sizes, int n_in,
                              void* d_out, int out_size, void* d_ws, size_t ws_size,
                              hipStream_t stream) {
    const float* q_z    = (const float*)d_in[0];
    const float* mu     = (const float*)d_in[1];
    const float* logvar = (const float*)d_in[2];
    float* out = (float*)d_out;

    float* tab = (float*)d_ws;          // 5120 floats
    float* C   = tab + 5120;            // 10 floats

    gmvae_prep<<<KK, DD, 0, stream>>>(mu, logvar, tab, C);
    gmvae_main<<<BB / 64, 256, 0, stream>>>(q_z, tab, C, out);
}